// Round 9
// baseline (99.190 us; speedup 1.0000x reference)
//
#include <hip/hip_runtime.h>

#define BINS 256
#define EMBV 64          // EMB/4 float4s per row
#define BH   8           // 2*4 flattened batch

typedef float f32x4 __attribute__((ext_vector_type(4)));

// out[bh][i][j][d] = (s_i+s_j)*0.5 + s_i*s_j + T[|i-j|][d]
//
// Decisive read-volume test at FIXED concurrency/store-structure:
// block = (bh, i-pair, j-half): 2048 blocks x 256 thr (same as R4/R8),
// rows {2p, 2p+1}, j in [h*128, h*128+128). Each sj load feeds both rows
// (reads 2.0 -> 1.5 B per output B). Wave (r,q)=tj stores one contiguous
// 64-j run of one row (R8 store structure). XCD-grouped: bh = blk&7.
__global__ __launch_bounds__(256) void outputhead_kernel(
        const f32x4* __restrict__ seq4,   // [BH][BINS][EMBV]
        const f32x4* __restrict__ tab4,   // [256][EMBV]
        f32x4* __restrict__ out4)         // [BH][BINS][BINS][EMBV]
{
    const int blk = blockIdx.x;
    const int bh  = blk & 7;            // XCD-grouped: one bh per XCD
    const int rem = blk >> 3;           // 0..255 = (i-pair, j-half)
    const int p   = rem >> 1;           // 0..127 row-pair
    const int h   = rem & 1;            // j-half
    const int i0  = p * 2;
    const int i1  = i0 + 1;
    const int t   = threadIdx.x;
    const int d4  = t & 63;
    const int tj  = t >> 6;             // 0..3 = (r, q)
    const int r   = tj >> 1;            // row within pair
    const int q   = tj & 1;             // j-quarter within half

    const size_t seq_bh_base = (size_t)bh * BINS * EMBV;

    const int i = i0 + r;
    const f32x4 si = seq4[seq_bh_base + (size_t)i * EMBV + d4];

    const size_t out_row = ((size_t)(bh * BINS + i)) * BINS * EMBV;

    const int jbase = h * 128 + q * 64;

    #pragma unroll 4
    for (int jo = 0; jo < 64; ++jo) {
        const int j    = jbase + jo;
        const int dist = (i > j) ? (i - j) : (j - i);

        const f32x4 sj = seq4[seq_bh_base + (size_t)j * EMBV + d4];
        const f32x4 tv = tab4[(size_t)dist * EMBV + d4];

        const f32x4 o = (si + sj) * 0.5f + si * sj + tv;

        out4[out_row + (size_t)j * EMBV + d4] = o;
    }
}

extern "C" void kernel_launch(void* const* d_in, const int* in_sizes, int n_in,
                              void* d_out, int out_size, void* d_ws, size_t ws_size,
                              hipStream_t stream) {
    const f32x4* seq4 = (const f32x4*)d_in[0];  // (2,4,256,256) fp32
    const f32x4* tab4 = (const f32x4*)d_in[1];  // (256,256) fp32
    f32x4* out4 = (f32x4*)d_out;                // (2,4,256,256,256) fp32

    dim3 grid(BH * 256);   // 2048 blocks: 8 bh x 128 pairs x 2 j-halves
    dim3 block(256);
    outputhead_kernel<<<grid, block, 0, stream>>>(seq4, tab4, out4);
}